// Round 1
// baseline (381.427 us; speedup 1.0000x reference)
//
#include <hip/hip_runtime.h>
#include <stdint.h>

typedef unsigned short u16;
typedef __attribute__((ext_vector_type(8))) short bf16x8;
typedef __attribute__((ext_vector_type(4))) float f32x4;

#define NN 8192
#define HH 256
#define KK 100
#define BB 32
#define LL 128
#define NPAD 1024   // padded conv-GEMM N (K*10 slices = 1000, padded)

__device__ __forceinline__ u16 f2bf(float x) {
  unsigned int u = __float_as_uint(x);
  u += 0x7fffu + ((u >> 16) & 1u);
  return (u16)(u >> 16);
}

// ---------------------------------------------------------------- embT: [256][8192] bf16 = emb^T
__global__ __launch_bounds__(256) void convert_embT(const float* __restrict__ emb,
                                                    u16* __restrict__ embT) {
  __shared__ float t[64][65];
  const int tid = threadIdx.x;
  const int k0 = blockIdx.x * 64, n0 = blockIdx.y * 64;
#pragma unroll
  for (int i = 0; i < 16; ++i) {
    int idx = i * 256 + tid;
    int r = idx >> 6, c = idx & 63;
    t[r][c] = emb[(size_t)(k0 + r) * HH + n0 + c];
  }
  __syncthreads();
#pragma unroll
  for (int i = 0; i < 16; ++i) {
    int idx = i * 256 + tid;
    int r = idx >> 6, c = idx & 63;
    embT[(size_t)(n0 + r) * NN + k0 + c] = f2bf(t[c][r]);
  }
}

// ---------------------------------------------------------------- layer1 = adj @ emb  (bf16 MFMA, split-K=4)
// grid (128, 4): x = m-tile (64 rows), y = K split. parts[y] += partial
__global__ __launch_bounds__(256) void gemm_layer1(const float* __restrict__ adj,
                                                   const u16* __restrict__ embT,
                                                   float* __restrict__ parts) {
  __shared__ __align__(16) u16 As[64 * 64];    // [m][k]
  __shared__ __align__(16) u16 Bs[256 * 64];   // [n][k]
  const int tid = threadIdx.x;
  const int wid = tid >> 6;
  const int lane = tid & 63;
  const int m0 = blockIdx.x * 64;
  const int kbeg = blockIdx.y * 2048;

  f32x4 acc[4][4];
  const f32x4 zf = {0.f, 0.f, 0.f, 0.f};
#pragma unroll
  for (int i = 0; i < 4; ++i)
#pragma unroll
    for (int j = 0; j < 4; ++j) acc[i][j] = zf;

  const int ra = tid >> 2;            // A row this thread stages
  const int kca = (tid & 3) << 4;     // 16 consecutive k per thread

  for (int k0 = kbeg; k0 < kbeg + 2048; k0 += 64) {
    // --- stage A: fp32 global -> bf16 LDS
    const float4* ap = reinterpret_cast<const float4*>(adj + (size_t)(m0 + ra) * NN + k0 + kca);
    float4 v0 = ap[0], v1 = ap[1], v2 = ap[2], v3 = ap[3];
    bf16x8 p0, p1;
    p0[0] = (short)f2bf(v0.x); p0[1] = (short)f2bf(v0.y); p0[2] = (short)f2bf(v0.z); p0[3] = (short)f2bf(v0.w);
    p0[4] = (short)f2bf(v1.x); p0[5] = (short)f2bf(v1.y); p0[6] = (short)f2bf(v1.z); p0[7] = (short)f2bf(v1.w);
    p1[0] = (short)f2bf(v2.x); p1[1] = (short)f2bf(v2.y); p1[2] = (short)f2bf(v2.z); p1[3] = (short)f2bf(v2.w);
    p1[4] = (short)f2bf(v3.x); p1[5] = (short)f2bf(v3.y); p1[6] = (short)f2bf(v3.z); p1[7] = (short)f2bf(v3.w);
    *reinterpret_cast<bf16x8*>(&As[ra * 64 + kca]) = p0;
    *reinterpret_cast<bf16x8*>(&As[ra * 64 + kca + 8]) = p1;
    // --- stage B: bf16 global (embT) -> LDS
#pragma unroll
    for (int i = 0; i < 8; ++i) {
      int c = i * 256 + tid;
      bf16x8 bv = *reinterpret_cast<const bf16x8*>(embT + (size_t)(c >> 3) * NN + k0 + ((c & 7) << 3));
      *reinterpret_cast<bf16x8*>(&Bs[c * 8]) = bv;
    }
    __syncthreads();
#pragma unroll
    for (int kk = 0; kk < 64; kk += 32) {
      const int krow = kk + ((lane >> 4) << 3);
      bf16x8 af[4], bfr[4];
#pragma unroll
      for (int mi = 0; mi < 4; ++mi)
        af[mi] = *reinterpret_cast<const bf16x8*>(&As[(mi * 16 + (lane & 15)) * 64 + krow]);
#pragma unroll
      for (int ni = 0; ni < 4; ++ni)
        bfr[ni] = *reinterpret_cast<const bf16x8*>(&Bs[(wid * 64 + ni * 16 + (lane & 15)) * 64 + krow]);
#pragma unroll
      for (int mi = 0; mi < 4; ++mi)
#pragma unroll
        for (int ni = 0; ni < 4; ++ni)
          acc[mi][ni] = __builtin_amdgcn_mfma_f32_16x16x32_bf16(af[mi], bfr[ni], acc[mi][ni], 0, 0, 0);
    }
    __syncthreads();
  }
  float* out = parts + (size_t)blockIdx.y * ((size_t)NN * HH);
  const int rbase = (lane >> 4) << 2;
  const int col0 = wid * 64 + (lane & 15);
#pragma unroll
  for (int mi = 0; mi < 4; ++mi)
#pragma unroll
    for (int ni = 0; ni < 4; ++ni)
#pragma unroll
      for (int r = 0; r < 4; ++r)
        out[(size_t)(m0 + mi * 16 + rbase + r) * HH + col0 + ni * 16] = acc[mi][ni][r];
}

// ---------------------------------------------------------------- gather: Q/A rows = sum of split-K parts
__global__ __launch_bounds__(256) void gather_qa(const float* __restrict__ parts,
                                                 const int* __restrict__ q_idx,
                                                 const int* __restrict__ a_idx,
                                                 float* __restrict__ Q, float* __restrict__ A) {
  const int rb = blockIdx.x;
  const bool isA = rb >= BB * LL;
  const int r = isA ? rb - BB * LL : rb;
  const int idx = (isA ? a_idx : q_idx)[r];
  const int tid = threadIdx.x;
  float s = 0.f;
#pragma unroll
  for (int p = 0; p < 4; ++p)
    s += parts[(size_t)p * ((size_t)NN * HH) + (size_t)idx * HH + tid];
  (isA ? A : Q)[(size_t)r * HH + tid] = s;
}

// ---------------------------------------------------------------- score[b,l,m] = dot256(Q[b,l], A[b,m])
__global__ __launch_bounds__(128) void score_kernel(const float* __restrict__ Q,
                                                    const float* __restrict__ A,
                                                    float* __restrict__ score) {
  __shared__ float qs[HH];
  const int bl = blockIdx.x;
  const int b = bl >> 7;
  const int tid = threadIdx.x;
  qs[tid] = Q[(size_t)bl * HH + tid];
  qs[tid + 128] = Q[(size_t)bl * HH + tid + 128];
  __syncthreads();
  const float4* a4 = reinterpret_cast<const float4*>(A + ((size_t)b * LL + tid) * HH);
  const float4* q4 = reinterpret_cast<const float4*>(qs);
  float acc = 0.f;
#pragma unroll 8
  for (int h = 0; h < HH / 4; ++h) {
    float4 av = a4[h], qv = q4[h];
    acc += av.x * qv.x + av.y * qv.y + av.z * qv.z + av.w * qv.w;
  }
  score[(size_t)bl * LL + tid] = acc;
}

// ---------------------------------------------------------------- softmax over m (rows) -> wq
__global__ __launch_bounds__(64) void softmax_row(const float* __restrict__ score,
                                                  float* __restrict__ wq) {
  const int bl = blockIdx.x;
  const int lane = threadIdx.x;
  const float* s = score + (size_t)bl * LL;
  float x0 = s[lane], x1 = s[lane + 64];
  float mx = fmaxf(x0, x1);
#pragma unroll
  for (int off = 32; off; off >>= 1) mx = fmaxf(mx, __shfl_xor(mx, off));
  float e0 = expf(x0 - mx), e1 = expf(x1 - mx);
  float sum = e0 + e1;
#pragma unroll
  for (int off = 32; off; off >>= 1) sum += __shfl_xor(sum, off);
  float inv = 1.f / sum;
  wq[(size_t)bl * LL + lane] = e0 * inv;
  wq[(size_t)bl * LL + lane + 64] = e1 * inv;
}

// ---------------------------------------------------------------- softmax over l (cols) -> waT[b][m][l]
__global__ __launch_bounds__(64) void softmax_col(const float* __restrict__ score,
                                                  float* __restrict__ waT) {
  const int bm = blockIdx.x;
  const int b = bm >> 7, m = bm & 127;
  const int lane = threadIdx.x;
  const float* s = score + (size_t)b * LL * LL + m;
  float x0 = s[(size_t)lane * LL], x1 = s[(size_t)(lane + 64) * LL];
  float mx = fmaxf(x0, x1);
#pragma unroll
  for (int off = 32; off; off >>= 1) mx = fmaxf(mx, __shfl_xor(mx, off));
  float e0 = expf(x0 - mx), e1 = expf(x1 - mx);
  float sum = e0 + e1;
#pragma unroll
  for (int off = 32; off; off >>= 1) sum += __shfl_xor(sum, off);
  float inv = 1.f / sum;
  waT[(size_t)bm * LL + lane] = e0 * inv;
  waT[(size_t)bm * LL + lane + 64] = e1 * inv;
}

// ---------------------------------------------------------------- EQ + tq build (rows 0..4095 of Tbf)
__global__ __launch_bounds__(256) void eq_tbuild(const float* __restrict__ wq,
                                                 const float* __restrict__ A,
                                                 const float* __restrict__ Q,
                                                 u16* __restrict__ Tbf) {
  __shared__ float w[LL];
  const int bl = blockIdx.x;
  const int b = bl >> 7;
  const int tid = threadIdx.x;
  if (tid < LL) w[tid] = wq[(size_t)bl * LL + tid];
  __syncthreads();
  const float* Ab = A + (size_t)b * LL * HH + tid;
  float acc = 0.f;
#pragma unroll 16
  for (int m = 0; m < LL; ++m) acc += w[m] * Ab[(size_t)m * HH];
  float q = Q[(size_t)bl * HH + tid];
  float d = q - acc;
  Tbf[(size_t)bl * 512 + tid] = f2bf(d * d);
  Tbf[(size_t)bl * 512 + 256 + tid] = f2bf(q * acc);
}

// ---------------------------------------------------------------- EA + ta build (rows 4096..8191 of Tbf)
__global__ __launch_bounds__(256) void ea_tbuild(const float* __restrict__ waT,
                                                 const float* __restrict__ Q,
                                                 const float* __restrict__ A,
                                                 u16* __restrict__ Tbf) {
  __shared__ float w[LL];
  const int bm = blockIdx.x;
  const int b = bm >> 7;
  const int tid = threadIdx.x;
  if (tid < LL) w[tid] = waT[(size_t)bm * LL + tid];
  __syncthreads();
  const float* Qb = Q + (size_t)b * LL * HH + tid;
  float acc = 0.f;
#pragma unroll 16
  for (int l = 0; l < LL; ++l) acc += w[l] * Qb[(size_t)l * HH];
  float a = A[(size_t)bm * HH + tid];
  float d = a - acc;
  Tbf[(size_t)(BB * LL + bm) * 512 + tid] = f2bf(d * d);
  Tbf[(size_t)(BB * LL + bm) * 512 + 256 + tid] = f2bf(a * acc);
}

// ---------------------------------------------------------------- Wcat bf16 [1024][512]: row kr=k*10+slice, cols 5..516 of conv_w
__global__ __launch_bounds__(256) void prep_wcat(const float* __restrict__ w0,
                                                 const float* __restrict__ w1,
                                                 const float* __restrict__ w2,
                                                 const float* __restrict__ w3,
                                                 u16* __restrict__ Wcat) {
  const int kr = blockIdx.x;
  const int tid = threadIdx.x;
  u16* out = Wcat + (size_t)kr * 512;
  if (kr >= KK * 10) {
    out[tid] = 0;
    out[tid + 256] = 0;
    return;
  }
  const int k = kr / 10, s = kr % 10;
  const float* w;
  int r, fs;
  if (s < 1)      { w = w0; r = s;     fs = 1; }
  else if (s < 3) { w = w1; r = s - 1; fs = 2; }
  else if (s < 6) { w = w2; r = s - 3; fs = 3; }
  else            { w = w3; r = s - 6; fs = 4; }
  const float* src = w + ((size_t)k * fs + r) * 522 + 5;
  out[tid] = f2bf(src[tid]);
  out[tid + 256] = f2bf(src[tid + 256]);
}

// ---------------------------------------------------------------- conv GEMM: D[8192][1024] = Tbf @ Wcat^T (bf16 MFMA)
// grid (128, 4): x = m-tile, y = n-tile (256 cols each)
__global__ __launch_bounds__(256) void gemm_conv(const u16* __restrict__ Tbf,
                                                 const u16* __restrict__ Wcat,
                                                 float* __restrict__ D) {
  __shared__ __align__(16) u16 As[64 * 64];
  __shared__ __align__(16) u16 Bs[256 * 64];
  const int tid = threadIdx.x;
  const int wid = tid >> 6;
  const int lane = tid & 63;
  const int m0 = blockIdx.x * 64;
  const int n0 = blockIdx.y * 256;

  f32x4 acc[4][4];
  const f32x4 zf = {0.f, 0.f, 0.f, 0.f};
#pragma unroll
  for (int i = 0; i < 4; ++i)
#pragma unroll
    for (int j = 0; j < 4; ++j) acc[i][j] = zf;

  for (int k0 = 0; k0 < 512; k0 += 64) {
#pragma unroll
    for (int i = 0; i < 2; ++i) {
      int c = i * 256 + tid;
      bf16x8 av = *reinterpret_cast<const bf16x8*>(Tbf + (size_t)(m0 + (c >> 3)) * 512 + k0 + ((c & 7) << 3));
      *reinterpret_cast<bf16x8*>(&As[c * 8]) = av;
    }
#pragma unroll
    for (int i = 0; i < 8; ++i) {
      int c = i * 256 + tid;
      bf16x8 bv = *reinterpret_cast<const bf16x8*>(Wcat + (size_t)(n0 + (c >> 3)) * 512 + k0 + ((c & 7) << 3));
      *reinterpret_cast<bf16x8*>(&Bs[c * 8]) = bv;
    }
    __syncthreads();
#pragma unroll
    for (int kk = 0; kk < 64; kk += 32) {
      const int krow = kk + ((lane >> 4) << 3);
      bf16x8 af[4], bfr[4];
#pragma unroll
      for (int mi = 0; mi < 4; ++mi)
        af[mi] = *reinterpret_cast<const bf16x8*>(&As[(mi * 16 + (lane & 15)) * 64 + krow]);
#pragma unroll
      for (int ni = 0; ni < 4; ++ni)
        bfr[ni] = *reinterpret_cast<const bf16x8*>(&Bs[(wid * 64 + ni * 16 + (lane & 15)) * 64 + krow]);
#pragma unroll
      for (int mi = 0; mi < 4; ++mi)
#pragma unroll
        for (int ni = 0; ni < 4; ++ni)
          acc[mi][ni] = __builtin_amdgcn_mfma_f32_16x16x32_bf16(af[mi], bfr[ni], acc[mi][ni], 0, 0, 0);
    }
    __syncthreads();
  }
  const int rbase = (lane >> 4) << 2;
  const int col0 = wid * 64 + (lane & 15);
#pragma unroll
  for (int mi = 0; mi < 4; ++mi)
#pragma unroll
    for (int ni = 0; ni < 4; ++ni)
#pragma unroll
      for (int r = 0; r < 4; ++r)
        D[(size_t)(m0 + mi * 16 + rbase + r) * NPAD + n0 + col0 + ni * 16] = acc[mi][ni][r];
}

// ---------------------------------------------------------------- shift-sum + bias + relu + maxpool -> re[32][800]
__global__ __launch_bounds__(256) void reduce_conv(const float* __restrict__ D,
                                                   const float* __restrict__ b0,
                                                   const float* __restrict__ b1,
                                                   const float* __restrict__ b2,
                                                   const float* __restrict__ b3,
                                                   float* __restrict__ re) {
  const int t = blockIdx.x * blockDim.x + threadIdx.x;
  if (t >= BB * 800) return;
  const int b = t / 800;
  const int rem = t % 800;
  const int sel = rem / 400;
  const int rem2 = rem % 400;
  const int f = rem2 / 100;
  const int k = rem2 % 100;
  const int offt[4] = {0, 1, 3, 6};
  const int fst[4] = {1, 2, 3, 4};
  const int fs = fst[f], off = offt[f];
  const float bias = (f == 0 ? b0 : f == 1 ? b1 : f == 2 ? b2 : b3)[k];
  const float* Drow = D + ((size_t)sel * (BB * LL) + (size_t)b * LL) * NPAD + k * 10 + off;
  const int outh = 139 - fs;
  float best = 0.f;  // relu floor
  for (int i = 0; i < outh; ++i) {
    float s = bias;
#pragma unroll 4
    for (int r = 0; r < 4; ++r) {
      if (r < fs) {
        int j = i + r - 5;
        if (j >= 0 && j < LL) s += Drow[(size_t)j * NPAD + r];
      }
    }
    best = fmaxf(best, fmaxf(s, 0.f));
  }
  re[(size_t)b * 800 + sel * 400 + f * 100 + k] = best;
}

// ---------------------------------------------------------------- dense + log_softmax -> out[32][2]
__global__ __launch_bounds__(64) void dense_logsm(const float* __restrict__ re,
                                                  const float* __restrict__ dw,
                                                  const float* __restrict__ db,
                                                  float* __restrict__ out) {
  const int t = threadIdx.x;
  const int b = t >> 1, c = t & 1;
  const float* r = re + (size_t)b * 800;
  float acc = db[c];
  for (int j = 0; j < 800; ++j) acc += r[j] * dw[j * 2 + c];
  float other = __shfl_xor(acc, 1);
  float mx = fmaxf(acc, other);
  float lse = mx + logf(expf(acc - mx) + expf(other - mx));
  out[b * 2 + c] = acc - lse;
}

// ---------------------------------------------------------------- workspace layout (bytes)
static const size_t OFF_PARTS = 0;                         // 4 * 8192*256 f32 = 33,554,432 B
static const size_t OFF_D     = 0;                         // alias (parts dead by conv time)
static const size_t OFF_Q     = 33554432;                  // 4,194,304 B
static const size_t OFF_A     = OFF_Q + 4194304;
static const size_t OFF_SCORE = OFF_A + 4194304;           // 2,097,152 B
static const size_t OFF_WQ    = OFF_SCORE + 2097152;
static const size_t OFF_WAT   = OFF_WQ + 2097152;
static const size_t OFF_RE    = OFF_WAT + 2097152;         // 102,400 B
static const size_t OFF_TBF   = OFF_RE + 102400;           // 8,388,608 B (bf16 [8192][512])
static const size_t OFF_WCAT  = OFF_TBF + 8388608;         // 1,048,576 B (bf16 [1024][512])
static const size_t OFF_EMBT  = OFF_WCAT + 1048576;        // 4,194,304 B (bf16 [256][8192])
// total ~62 MB

extern "C" void kernel_launch(void* const* d_in, const int* in_sizes, int n_in,
                              void* d_out, int out_size, void* d_ws, size_t ws_size,
                              hipStream_t stream) {
  (void)in_sizes; (void)n_in; (void)out_size; (void)ws_size;
  const float* adj  = (const float*)d_in[0];
  const float* emb  = (const float*)d_in[1];
  const int* q_idx  = (const int*)d_in[2];
  const int* a_idx  = (const int*)d_in[3];
  const float* cw0 = (const float*)d_in[4];
  const float* cb0 = (const float*)d_in[5];
  const float* cw1 = (const float*)d_in[6];
  const float* cb1 = (const float*)d_in[7];
  const float* cw2 = (const float*)d_in[8];
  const float* cb2 = (const float*)d_in[9];
  const float* cw3 = (const float*)d_in[10];
  const float* cb3 = (const float*)d_in[11];
  const float* dw = (const float*)d_in[12];
  const float* db = (const float*)d_in[13];
  float* out = (float*)d_out;

  char* ws = (char*)d_ws;
  float* parts = (float*)(ws + OFF_PARTS);
  float* Dbuf  = (float*)(ws + OFF_D);
  float* Q     = (float*)(ws + OFF_Q);
  float* Abuf  = (float*)(ws + OFF_A);
  float* score = (float*)(ws + OFF_SCORE);
  float* wq    = (float*)(ws + OFF_WQ);
  float* waT   = (float*)(ws + OFF_WAT);
  float* re    = (float*)(ws + OFF_RE);
  u16* Tbf     = (u16*)(ws + OFF_TBF);
  u16* Wcat    = (u16*)(ws + OFF_WCAT);
  u16* embT    = (u16*)(ws + OFF_EMBT);

  convert_embT<<<dim3(128, 4), 256, 0, stream>>>(emb, embT);
  prep_wcat<<<1024, 256, 0, stream>>>(cw0, cw1, cw2, cw3, Wcat);
  gemm_layer1<<<dim3(128, 4), 256, 0, stream>>>(adj, embT, parts);
  gather_qa<<<2 * BB * LL, 256, 0, stream>>>(parts, q_idx, a_idx, Q, Abuf);
  score_kernel<<<BB * LL, 128, 0, stream>>>(Q, Abuf, score);
  softmax_row<<<BB * LL, 64, 0, stream>>>(score, wq);
  softmax_col<<<BB * LL, 64, 0, stream>>>(score, waT);
  eq_tbuild<<<BB * LL, 256, 0, stream>>>(wq, Abuf, Q, Tbf);
  ea_tbuild<<<BB * LL, 256, 0, stream>>>(waT, Q, Abuf, Tbf);
  gemm_conv<<<dim3(128, 4), 256, 0, stream>>>(Tbf, Wcat, Dbuf);
  reduce_conv<<<100, 256, 0, stream>>>(Dbuf, cb0, cb1, cb2, cb3, re);
  dense_logsm<<<1, 64, 0, stream>>>(re, dw, db, out);
}

// Round 2
// 289.711 us; speedup vs baseline: 1.3166x; 1.3166x over previous
//
#include <hip/hip_runtime.h>
#include <hip/hip_bf16.h>
#include <stdint.h>

typedef unsigned short u16;
typedef __attribute__((ext_vector_type(8))) short bf16x8;
typedef __attribute__((ext_vector_type(4))) float f32x4;

#define NN 8192
#define HH 256
#define KK 100
#define BB 32
#define LL 128
#define NPAD 1024   // padded conv-GEMM N (K*10 slices = 1000, padded)
#define SPLITK 8
#define KCH (NN / SPLITK)   // 1024

__device__ __forceinline__ u16 f2bf_rne(float x) {
  union { __hip_bfloat16 h; u16 u; } v;
  v.h = __float2bfloat16(x);   // RNE; compiler can pack pairs into v_cvt_pk_bf16_f32
  return v.u;
}

// ---------------------------------------------------------------- embT: [256][8192] bf16 = emb^T
__global__ __launch_bounds__(256) void convert_embT(const float* __restrict__ emb,
                                                    u16* __restrict__ embT) {
  __shared__ float t[64][65];
  const int tid = threadIdx.x;
  const int k0 = blockIdx.x * 64, n0 = blockIdx.y * 64;
#pragma unroll
  for (int i = 0; i < 16; ++i) {
    int idx = i * 256 + tid;
    int r = idx >> 6, c = idx & 63;
    t[r][c] = emb[(size_t)(k0 + r) * HH + n0 + c];
  }
  __syncthreads();
#pragma unroll
  for (int i = 0; i < 16; ++i) {
    int idx = i * 256 + tid;
    int r = idx >> 6, c = idx & 63;
    embT[(size_t)(n0 + r) * NN + k0 + c] = f2bf_rne(t[c][r]);
  }
}

// ---------------------------------------------------------------- layer1 = adj @ emb  (bf16 MFMA)
// BM=128, BN=256, BK=64, 512 threads (8 waves, 2Mx4N), split-K=8. grid (64, 8)
__global__ __launch_bounds__(512) void gemm_layer1(const float* __restrict__ adj,
                                                   const u16* __restrict__ embT,
                                                   float* __restrict__ parts) {
  __shared__ __align__(16) u16 As[128 * 64];   // [m][k] XOR-swizzled
  __shared__ __align__(16) u16 Bs[256 * 64];   // [n][k] XOR-swizzled
  const int tid = threadIdx.x;
  const int wid = tid >> 6;
  const int lane = tid & 63;
  const int wm = wid >> 2, wn = wid & 3;
  const int m0 = blockIdx.x * 128;
  const int kbeg = blockIdx.y * KCH;

  f32x4 acc[4][4];
  const f32x4 zf = {0.f, 0.f, 0.f, 0.f};
#pragma unroll
  for (int i = 0; i < 4; ++i)
#pragma unroll
    for (int j = 0; j < 4; ++j) acc[i][j] = zf;

  const int ra = tid >> 2;            // A row this thread stages (0..127)
  const int kca = (tid & 3) << 4;     // 16 consecutive k per thread
  const int swa = (ra & 7) << 3;

  for (int k0 = kbeg; k0 < kbeg + KCH; k0 += 64) {
    // --- stage A: fp32 global -> bf16 LDS (swizzled)
    const float4* ap = reinterpret_cast<const float4*>(adj + (size_t)(m0 + ra) * NN + k0 + kca);
    float4 v0 = ap[0], v1 = ap[1], v2 = ap[2], v3 = ap[3];
    bf16x8 p0, p1;
    p0[0] = (short)f2bf_rne(v0.x); p0[1] = (short)f2bf_rne(v0.y); p0[2] = (short)f2bf_rne(v0.z); p0[3] = (short)f2bf_rne(v0.w);
    p0[4] = (short)f2bf_rne(v1.x); p0[5] = (short)f2bf_rne(v1.y); p0[6] = (short)f2bf_rne(v1.z); p0[7] = (short)f2bf_rne(v1.w);
    p1[0] = (short)f2bf_rne(v2.x); p1[1] = (short)f2bf_rne(v2.y); p1[2] = (short)f2bf_rne(v2.z); p1[3] = (short)f2bf_rne(v2.w);
    p1[4] = (short)f2bf_rne(v3.x); p1[5] = (short)f2bf_rne(v3.y); p1[6] = (short)f2bf_rne(v3.z); p1[7] = (short)f2bf_rne(v3.w);
    *reinterpret_cast<bf16x8*>(&As[ra * 64 + (kca ^ swa)]) = p0;
    *reinterpret_cast<bf16x8*>(&As[ra * 64 + ((kca + 8) ^ swa)]) = p1;
    // --- stage B: bf16 global (embT) -> LDS (swizzled)
#pragma unroll
    for (int i = 0; i < 4; ++i) {
      int c = i * 512 + tid;
      int row = c >> 3, sub = (c & 7) << 3;
      bf16x8 bv = *reinterpret_cast<const bf16x8*>(embT + (size_t)row * NN + k0 + sub);
      *reinterpret_cast<bf16x8*>(&Bs[row * 64 + (sub ^ ((row & 7) << 3))]) = bv;
    }
    __syncthreads();
#pragma unroll
    for (int kk = 0; kk < 64; kk += 32) {
      const int krow = kk + ((lane >> 4) << 3);
      bf16x8 af[4], bfr[4];
#pragma unroll
      for (int mi = 0; mi < 4; ++mi) {
        int row = wm * 64 + mi * 16 + (lane & 15);
        af[mi] = *reinterpret_cast<const bf16x8*>(&As[row * 64 + (krow ^ ((row & 7) << 3))]);
      }
#pragma unroll
      for (int ni = 0; ni < 4; ++ni) {
        int row = wn * 64 + ni * 16 + (lane & 15);
        bfr[ni] = *reinterpret_cast<const bf16x8*>(&Bs[row * 64 + (krow ^ ((row & 7) << 3))]);
      }
#pragma unroll
      for (int mi = 0; mi < 4; ++mi)
#pragma unroll
        for (int ni = 0; ni < 4; ++ni)
          acc[mi][ni] = __builtin_amdgcn_mfma_f32_16x16x32_bf16(af[mi], bfr[ni], acc[mi][ni], 0, 0, 0);
    }
    __syncthreads();
  }
  float* out = parts + (size_t)blockIdx.y * ((size_t)NN * HH);
  const int rbase = (lane >> 4) << 2;
#pragma unroll
  for (int mi = 0; mi < 4; ++mi)
#pragma unroll
    for (int ni = 0; ni < 4; ++ni)
#pragma unroll
      for (int r = 0; r < 4; ++r)
        out[(size_t)(m0 + wm * 64 + mi * 16 + rbase + r) * HH + wn * 64 + ni * 16 + (lane & 15)] = acc[mi][ni][r];
}

// ---------------------------------------------------------------- gather: Q/A rows = sum of split-K parts
__global__ __launch_bounds__(256) void gather_qa(const float* __restrict__ parts,
                                                 const int* __restrict__ q_idx,
                                                 const int* __restrict__ a_idx,
                                                 float* __restrict__ Q, float* __restrict__ A) {
  const int rb = blockIdx.x;
  const bool isA = rb >= BB * LL;
  const int r = isA ? rb - BB * LL : rb;
  const int idx = (isA ? a_idx : q_idx)[r];
  const int tid = threadIdx.x;
  float s = 0.f;
#pragma unroll
  for (int p = 0; p < SPLITK; ++p)
    s += parts[(size_t)p * ((size_t)NN * HH) + (size_t)idx * HH + tid];
  (isA ? A : Q)[(size_t)r * HH + tid] = s;
}

// ---------------------------------------------------------------- score[b,l,m] = dot256(Q[b,l], A[b,m])
__global__ __launch_bounds__(128) void score_kernel(const float* __restrict__ Q,
                                                    const float* __restrict__ A,
                                                    float* __restrict__ score) {
  __shared__ float qs[HH];
  const int bl = blockIdx.x;
  const int b = bl >> 7;
  const int tid = threadIdx.x;
  qs[tid] = Q[(size_t)bl * HH + tid];
  qs[tid + 128] = Q[(size_t)bl * HH + tid + 128];
  __syncthreads();
  const float4* a4 = reinterpret_cast<const float4*>(A + ((size_t)b * LL + tid) * HH);
  const float4* q4 = reinterpret_cast<const float4*>(qs);
  float acc = 0.f;
#pragma unroll 8
  for (int h = 0; h < HH / 4; ++h) {
    float4 av = a4[h], qv = q4[h];
    acc += av.x * qv.x + av.y * qv.y + av.z * qv.z + av.w * qv.w;
  }
  score[(size_t)bl * LL + tid] = acc;
}

// ---------------------------------------------------------------- softmax over m (rows) -> wq
__global__ __launch_bounds__(64) void softmax_row(const float* __restrict__ score,
                                                  float* __restrict__ wq) {
  const int bl = blockIdx.x;
  const int lane = threadIdx.x;
  const float* s = score + (size_t)bl * LL;
  float x0 = s[lane], x1 = s[lane + 64];
  float mx = fmaxf(x0, x1);
#pragma unroll
  for (int off = 32; off; off >>= 1) mx = fmaxf(mx, __shfl_xor(mx, off));
  float e0 = expf(x0 - mx), e1 = expf(x1 - mx);
  float sum = e0 + e1;
#pragma unroll
  for (int off = 32; off; off >>= 1) sum += __shfl_xor(sum, off);
  float inv = 1.f / sum;
  wq[(size_t)bl * LL + lane] = e0 * inv;
  wq[(size_t)bl * LL + lane + 64] = e1 * inv;
}

// ---------------------------------------------------------------- softmax over l (cols) -> waT[b][m][l]
__global__ __launch_bounds__(64) void softmax_col(const float* __restrict__ score,
                                                  float* __restrict__ waT) {
  const int bm = blockIdx.x;
  const int b = bm >> 7, m = bm & 127;
  const int lane = threadIdx.x;
  const float* s = score + (size_t)b * LL * LL + m;
  float x0 = s[(size_t)lane * LL], x1 = s[(size_t)(lane + 64) * LL];
  float mx = fmaxf(x0, x1);
#pragma unroll
  for (int off = 32; off; off >>= 1) mx = fmaxf(mx, __shfl_xor(mx, off));
  float e0 = expf(x0 - mx), e1 = expf(x1 - mx);
  float sum = e0 + e1;
#pragma unroll
  for (int off = 32; off; off >>= 1) sum += __shfl_xor(sum, off);
  float inv = 1.f / sum;
  waT[(size_t)bm * LL + lane] = e0 * inv;
  waT[(size_t)bm * LL + lane + 64] = e1 * inv;
}

// ---------------------------------------------------------------- EQ + tq build (rows 0..4095 of Tbf)
__global__ __launch_bounds__(256) void eq_tbuild(const float* __restrict__ wq,
                                                 const float* __restrict__ A,
                                                 const float* __restrict__ Q,
                                                 u16* __restrict__ Tbf) {
  __shared__ float w[LL];
  const int bl = blockIdx.x;
  const int b = bl >> 7;
  const int tid = threadIdx.x;
  if (tid < LL) w[tid] = wq[(size_t)bl * LL + tid];
  __syncthreads();
  const float* Ab = A + (size_t)b * LL * HH + tid;
  float acc = 0.f;
#pragma unroll 16
  for (int m = 0; m < LL; ++m) acc += w[m] * Ab[(size_t)m * HH];
  float q = Q[(size_t)bl * HH + tid];
  float d = q - acc;
  Tbf[(size_t)bl * 512 + tid] = f2bf_rne(d * d);
  Tbf[(size_t)bl * 512 + 256 + tid] = f2bf_rne(q * acc);
}

// ---------------------------------------------------------------- EA + ta build (rows 4096..8191 of Tbf)
__global__ __launch_bounds__(256) void ea_tbuild(const float* __restrict__ waT,
                                                 const float* __restrict__ Q,
                                                 const float* __restrict__ A,
                                                 u16* __restrict__ Tbf) {
  __shared__ float w[LL];
  const int bm = blockIdx.x;
  const int b = bm >> 7;
  const int tid = threadIdx.x;
  if (tid < LL) w[tid] = waT[(size_t)bm * LL + tid];
  __syncthreads();
  const float* Qb = Q + (size_t)b * LL * HH + tid;
  float acc = 0.f;
#pragma unroll 16
  for (int l = 0; l < LL; ++l) acc += w[l] * Qb[(size_t)l * HH];
  float a = A[(size_t)bm * HH + tid];
  float d = a - acc;
  Tbf[(size_t)(BB * LL + bm) * 512 + tid] = f2bf_rne(d * d);
  Tbf[(size_t)(BB * LL + bm) * 512 + 256 + tid] = f2bf_rne(a * acc);
}

// ---------------------------------------------------------------- Wcat bf16 [1024][512]
__global__ __launch_bounds__(256) void prep_wcat(const float* __restrict__ w0,
                                                 const float* __restrict__ w1,
                                                 const float* __restrict__ w2,
                                                 const float* __restrict__ w3,
                                                 u16* __restrict__ Wcat) {
  const int kr = blockIdx.x;
  const int tid = threadIdx.x;
  u16* out = Wcat + (size_t)kr * 512;
  if (kr >= KK * 10) {
    out[tid] = 0;
    out[tid + 256] = 0;
    return;
  }
  const int k = kr / 10, s = kr % 10;
  const float* w;
  int r, fs;
  if (s < 1)      { w = w0; r = s;     fs = 1; }
  else if (s < 3) { w = w1; r = s - 1; fs = 2; }
  else if (s < 6) { w = w2; r = s - 3; fs = 3; }
  else            { w = w3; r = s - 6; fs = 4; }
  const float* src = w + ((size_t)k * fs + r) * 522 + 5;
  out[tid] = f2bf_rne(src[tid]);
  out[tid + 256] = f2bf_rne(src[tid + 256]);
}

// ---------------------------------------------------------------- conv GEMM: D[8192][1024] = Tbf @ Wcat^T
// BM=128, BN=256, 512 threads, grid (64, 4)
__global__ __launch_bounds__(512) void gemm_conv(const u16* __restrict__ Tbf,
                                                 const u16* __restrict__ Wcat,
                                                 float* __restrict__ D) {
  __shared__ __align__(16) u16 As[128 * 64];
  __shared__ __align__(16) u16 Bs[256 * 64];
  const int tid = threadIdx.x;
  const int wid = tid >> 6;
  const int lane = tid & 63;
  const int wm = wid >> 2, wn = wid & 3;
  const int m0 = blockIdx.x * 128;
  const int n0 = blockIdx.y * 256;

  f32x4 acc[4][4];
  const f32x4 zf = {0.f, 0.f, 0.f, 0.f};
#pragma unroll
  for (int i = 0; i < 4; ++i)
#pragma unroll
    for (int j = 0; j < 4; ++j) acc[i][j] = zf;

  const int ra = tid >> 2;
  const int kca = (tid & 3) << 4;
  const int swa = (ra & 7) << 3;

  for (int k0 = 0; k0 < 512; k0 += 64) {
    const u16* arow = Tbf + (size_t)(m0 + ra) * 512 + k0 + kca;
    bf16x8 a0 = *reinterpret_cast<const bf16x8*>(arow);
    bf16x8 a1 = *reinterpret_cast<const bf16x8*>(arow + 8);
    *reinterpret_cast<bf16x8*>(&As[ra * 64 + (kca ^ swa)]) = a0;
    *reinterpret_cast<bf16x8*>(&As[ra * 64 + ((kca + 8) ^ swa)]) = a1;
#pragma unroll
    for (int i = 0; i < 4; ++i) {
      int c = i * 512 + tid;
      int row = c >> 3, sub = (c & 7) << 3;
      bf16x8 bv = *reinterpret_cast<const bf16x8*>(Wcat + (size_t)(n0 + row) * 512 + k0 + sub);
      *reinterpret_cast<bf16x8*>(&Bs[row * 64 + (sub ^ ((row & 7) << 3))]) = bv;
    }
    __syncthreads();
#pragma unroll
    for (int kk = 0; kk < 64; kk += 32) {
      const int krow = kk + ((lane >> 4) << 3);
      bf16x8 af[4], bfr[4];
#pragma unroll
      for (int mi = 0; mi < 4; ++mi) {
        int row = wm * 64 + mi * 16 + (lane & 15);
        af[mi] = *reinterpret_cast<const bf16x8*>(&As[row * 64 + (krow ^ ((row & 7) << 3))]);
      }
#pragma unroll
      for (int ni = 0; ni < 4; ++ni) {
        int row = wn * 64 + ni * 16 + (lane & 15);
        bfr[ni] = *reinterpret_cast<const bf16x8*>(&Bs[row * 64 + (krow ^ ((row & 7) << 3))]);
      }
#pragma unroll
      for (int mi = 0; mi < 4; ++mi)
#pragma unroll
        for (int ni = 0; ni < 4; ++ni)
          acc[mi][ni] = __builtin_amdgcn_mfma_f32_16x16x32_bf16(af[mi], bfr[ni], acc[mi][ni], 0, 0, 0);
    }
    __syncthreads();
  }
  const int rbase = (lane >> 4) << 2;
#pragma unroll
  for (int mi = 0; mi < 4; ++mi)
#pragma unroll
    for (int ni = 0; ni < 4; ++ni)
#pragma unroll
      for (int r = 0; r < 4; ++r)
        D[(size_t)(m0 + wm * 64 + mi * 16 + rbase + r) * NPAD + n0 + wn * 64 + ni * 16 + (lane & 15)] = acc[mi][ni][r];
}

// ---------------------------------------------------------------- shift-sum + bias + relu + maxpool -> re[32][800]
// block = (kchunk, selb-pair); stages [128][100] D tile via LDS, wave per output
__global__ __launch_bounds__(256) void reduce_conv(const float* __restrict__ D,
                                                   const float* __restrict__ b0,
                                                   const float* __restrict__ b1,
                                                   const float* __restrict__ b2,
                                                   const float* __restrict__ b3,
                                                   float* __restrict__ re) {
  __shared__ float tile[128][101];
  const int pair = blockIdx.y;           // 0..63
  const int sel = pair >> 5, b = pair & 31;
  const int kc = blockIdx.x;             // 0..9
  const int tid = threadIdx.x;
  const int rowbase = sel * (BB * LL) + b * LL;
  const int c0 = kc * 100;
  for (int idx = tid; idx < 12800; idx += 256) {
    int r = idx / 100, c = idx - r * 100;
    tile[r][c] = D[(size_t)(rowbase + r) * NPAD + c0 + c];
  }
  __syncthreads();
  const int wid = tid >> 6, lane = tid & 63;
  const int offt[4] = {0, 1, 3, 6};
  const int fst[4] = {1, 2, 3, 4};
  for (int o = wid; o < 40; o += 4) {
    const int kk = o >> 2, f = o & 3;
    const int fs = fst[f], off = offt[f];
    const int kg = kc * 10 + kk;
    const float bias = (f == 0 ? b0 : f == 1 ? b1 : f == 2 ? b2 : b3)[kg];
    const int col = kk * 10 + off;
    const int outh = 139 - fs;
    float best = 0.f;  // relu floor
    for (int i = lane; i < outh; i += 64) {
      float s = bias;
#pragma unroll 4
      for (int r = 0; r < 4; ++r) {
        if (r < fs) {
          int j = i + r - 5;
          if (j >= 0 && j < LL) s += tile[j][col + r];
        }
      }
      best = fmaxf(best, s);
    }
    best = fmaxf(best, 0.f);
#pragma unroll
    for (int d = 32; d; d >>= 1) best = fmaxf(best, __shfl_xor(best, d));
    if (lane == 0) re[(size_t)b * 800 + sel * 400 + f * 100 + kg] = best;
  }
}

// ---------------------------------------------------------------- dense + log_softmax -> out[32][2], wave per b
__global__ __launch_bounds__(64) void dense_logsm(const float* __restrict__ re,
                                                  const float* __restrict__ dw,
                                                  const float* __restrict__ db,
                                                  float* __restrict__ out) {
  const int b = blockIdx.x;
  const int lane = threadIdx.x;
  const float* r = re + (size_t)b * 800;
  float a0 = 0.f, a1 = 0.f;
  for (int j = lane; j < 800; j += 64) {
    float rv = r[j];
    a0 += rv * dw[j * 2];
    a1 += rv * dw[j * 2 + 1];
  }
#pragma unroll
  for (int d = 32; d; d >>= 1) {
    a0 += __shfl_xor(a0, d);
    a1 += __shfl_xor(a1, d);
  }
  if (lane == 0) {
    a0 += db[0];
    a1 += db[1];
    float mx = fmaxf(a0, a1);
    float lse = mx + logf(expf(a0 - mx) + expf(a1 - mx));
    out[b * 2] = a0 - lse;
    out[b * 2 + 1] = a1 - lse;
  }
}

// ---------------------------------------------------------------- workspace layout (bytes)
static const size_t OFF_PARTS = 0;                         // 8 * 8192*256 f32 = 67,108,864 B
static const size_t OFF_D     = 0;                         // alias (parts dead by conv time)
static const size_t OFF_Q     = 67108864;                  // 4,194,304 B
static const size_t OFF_A     = OFF_Q + 4194304;
static const size_t OFF_SCORE = OFF_A + 4194304;           // 2,097,152 B
static const size_t OFF_WQ    = OFF_SCORE + 2097152;
static const size_t OFF_WAT   = OFF_WQ + 2097152;
static const size_t OFF_RE    = OFF_WAT + 2097152;         // 102,400 B
static const size_t OFF_TBF   = OFF_RE + 102400;           // 8,388,608 B (bf16 [8192][512])
static const size_t OFF_WCAT  = OFF_TBF + 8388608;         // 1,048,576 B (bf16 [1024][512])
static const size_t OFF_EMBT  = OFF_WCAT + 1048576;        // 4,194,304 B (bf16 [256][8192])

extern "C" void kernel_launch(void* const* d_in, const int* in_sizes, int n_in,
                              void* d_out, int out_size, void* d_ws, size_t ws_size,
                              hipStream_t stream) {
  (void)in_sizes; (void)n_in; (void)out_size; (void)ws_size;
  const float* adj  = (const float*)d_in[0];
  const float* emb  = (const float*)d_in[1];
  const int* q_idx  = (const int*)d_in[2];
  const int* a_idx  = (const int*)d_in[3];
  const float* cw0 = (const float*)d_in[4];
  const float* cb0 = (const float*)d_in[5];
  const float* cw1 = (const float*)d_in[6];
  const float* cb1 = (const float*)d_in[7];
  const float* cw2 = (const float*)d_in[8];
  const float* cb2 = (const float*)d_in[9];
  const float* cw3 = (const float*)d_in[10];
  const float* cb3 = (const float*)d_in[11];
  const float* dw = (const float*)d_in[12];
  const float* db = (const float*)d_in[13];
  float* out = (float*)d_out;

  char* ws = (char*)d_ws;
  float* parts = (float*)(ws + OFF_PARTS);
  float* Dbuf  = (float*)(ws + OFF_D);
  float* Q     = (float*)(ws + OFF_Q);
  float* Abuf  = (float*)(ws + OFF_A);
  float* score = (float*)(ws + OFF_SCORE);
  float* wq    = (float*)(ws + OFF_WQ);
  float* waT   = (float*)(ws + OFF_WAT);
  float* re    = (float*)(ws + OFF_RE);
  u16* Tbf     = (u16*)(ws + OFF_TBF);
  u16* Wcat    = (u16*)(ws + OFF_WCAT);
  u16* embT    = (u16*)(ws + OFF_EMBT);

  convert_embT<<<dim3(128, 4), 256, 0, stream>>>(emb, embT);
  prep_wcat<<<1024, 256, 0, stream>>>(cw0, cw1, cw2, cw3, Wcat);
  gemm_layer1<<<dim3(64, SPLITK), 512, 0, stream>>>(adj, embT, parts);
  gather_qa<<<2 * BB * LL, 256, 0, stream>>>(parts, q_idx, a_idx, Q, Abuf);
  score_kernel<<<BB * LL, 128, 0, stream>>>(Q, Abuf, score);
  softmax_row<<<BB * LL, 64, 0, stream>>>(score, wq);
  softmax_col<<<BB * LL, 64, 0, stream>>>(score, waT);
  eq_tbuild<<<BB * LL, 256, 0, stream>>>(wq, Abuf, Q, Tbf);
  ea_tbuild<<<BB * LL, 256, 0, stream>>>(waT, Q, Abuf, Tbf);
  gemm_conv<<<dim3(64, 4), 512, 0, stream>>>(Tbf, Wcat, Dbuf);
  reduce_conv<<<dim3(10, 64), 256, 0, stream>>>(Dbuf, cb0, cb1, cb2, cb3, re);
  dense_logsm<<<BB, 64, 0, stream>>>(re, dw, db, out);
}